// Round 11
// baseline (92.964 us; speedup 1.0000x reference)
//
#include <hip/hip_runtime.h>

#define N_PARTS 62
#define M_SAMP  512
#define D_DIM   256
#define MARGIN  0.2f
#define ROWS    (N_PARTS * M_SAMP)   // 31744
#define PART_ELEMS (M_SAMP * D_DIM)  // 131072 bf16 per part

typedef unsigned short ushort_t;
typedef __attribute__((ext_vector_type(8))) short bf16x8;   // 8 bf16 = 4 VGPRs
typedef __attribute__((ext_vector_type(4))) float f32x4;

__device__ __forceinline__ ushort_t bf16_rne(float f) {
    unsigned u = __float_as_uint(f);
    unsigned r = u + 0x7fffu + ((u >> 16) & 1u);
    return (ushort_t)(r >> 16);
}

// K1: fp32 -> bf16 (RNE), per-row sum-of-squares of ROUNDED values, zero-init
// d_out. XCD-AFFINE grid: id = rb*64 + n -> XCD = id%8 = n%8, SAME mapping as
// the fused kernel, so part n's Fb/sq lines stay dirty in the LOCAL XCD L2
// and fused's frag loads never cross the (drain-congested) L3.
// FRAGMENT-MAJOR output: per (part, chunk c=k>>5, row-group g=row>>4) a
// contiguous 1 KB frag block; consuming lane l reads
//   F[g*16+(l&15)][c*32+(l>>4)*8..+7]  at  base + l*16 B.
__global__ __launch_bounds__(256) void prep_kernel(const float* __restrict__ feat,
                                                   ushort_t* __restrict__ Fb,
                                                   float* __restrict__ sq,
                                                   float* __restrict__ out) {
    const int id = blockIdx.x;       // id = rb*64 + n
    const int n  = id & 63;          // part (XCD affinity: id%8 == n%8)
    const int rb = id >> 6;          // row-quad within part (0..127)
    if (id == 0 && threadIdx.x < 2 * N_PARTS) out[threadIdx.x] = 0.0f;
    if (n >= N_PARTS) return;
    const int wv   = threadIdx.x >> 6;            // wave -> one row
    const int lane = threadIdx.x & 63;
    const int rp   = rb * 4 + wv;                 // part-local row
    const int row  = n * M_SAMP + rp;             // global row
    const float4 v = ((const float4*)(feat + (size_t)row * D_DIM))[lane];
    ushort4 us;
    us.x = bf16_rne(v.x); us.y = bf16_rne(v.y);
    us.z = bf16_rne(v.z); us.w = bf16_rne(v.w);
    const float fx = __uint_as_float((unsigned)us.x << 16);
    const float fy = __uint_as_float((unsigned)us.y << 16);
    const float fz = __uint_as_float((unsigned)us.z << 16);
    const float fw = __uint_as_float((unsigned)us.w << 16);
    // lane covers k = lane*4 .. +3: c = lane>>3, quad = (lane>>1)&3
    const int c  = lane >> 3;
    const int q  = (lane >> 1) & 3;
    const int g  = rp >> 4;
    const int fl = (rp & 15) | (q << 4);          // frag lane
    *(ushort4*)(Fb + (size_t)n * PART_ELEMS + ((size_t)(c * 32 + g) * 512)
                + fl * 8 + (lane & 1) * 4) = us;
    float ssum = fx * fx + fy * fy + fz * fz + fw * fw;
    #pragma unroll
    for (int off = 32; off > 0; off >>= 1) ssum += __shfl_xor(ssum, off);
    if (lane == 0) sq[row] = ssum;
}

// K2 (identical to R10): transposed-reduction fused kernel. Block = (part n,
// col-slab ct of 64 cols); wave w owns rows w*64..+63 (acc[4][4]). Stats fold
// over registers (dist symmetry: per-column == per-row), 2 butterfly steps.
__global__ __launch_bounds__(512, 4) void fused_triplet_kernel(const ushort_t* __restrict__ Fb,
                                                               const float* __restrict__ sq,
                                                               float* __restrict__ out) {
    const int id = blockIdx.x;
    const int n  = id & 63;          // part (XCD affinity: id%8 == n%8)
    const int ct = id >> 6;          // col-slab (64 cols)
    if (n >= N_PARTS) return;
    const int tid = threadIdx.x;
    const int wave = tid >> 6, lane = tid & 63;
    const ushort_t* F = Fb + (size_t)n * PART_ELEMS;
    const float* SQ = sq + n * M_SAMP;

    __shared__ float mrg[8][64][3];   // [wave][slab-local col][hp,hn,ds]

    f32x4 acc[4][4] = {};

    const ushort_t* aptr = F + (size_t)(wave * 4) * 512 + lane * 8;   // A: rows w*64..
    const ushort_t* bptr = F + (size_t)(ct * 4) * 512 + lane * 8;     // B: slab cols

    #pragma unroll
    for (int c = 0; c < 8; ++c) {
        const size_t off = (size_t)c * (32 * 512);
        bf16x8 af[4], bf[4];
        #pragma unroll
        for (int i = 0; i < 4; ++i) {
            af[i] = *(const bf16x8*)(aptr + off + (size_t)i * 512);
            bf[i] = *(const bf16x8*)(bptr + off + (size_t)i * 512);
        }
        #pragma unroll
        for (int mi = 0; mi < 4; ++mi)
            #pragma unroll
            for (int ni = 0; ni < 4; ++ni)
                acc[mi][ni] = __builtin_amdgcn_mfma_f32_16x16x32_bf16(
                    af[mi], bf[ni], acc[mi][ni], 0, 0, 0);
    }

    // Epilogue. C/D layout: col = lane&15, row = (lane>>4)*4 + reg.
    float sqr[4][4];
    #pragma unroll
    for (int mi = 0; mi < 4; ++mi)
        #pragma unroll
        for (int p = 0; p < 4; ++p)
            sqr[mi][p] = SQ[wave * 64 + mi * 16 + (lane >> 4) * 4 + p];

    #pragma unroll
    for (int ni = 0; ni < 4; ++ni) {
        const int C = ct * 64 + ni * 16 + (lane & 15);   // part-local col
        const float sc = SQ[C];
        const int Cg = C >> 3;                            // label = m>>3
        float ds = 0.f, hp = 0.f, hn = 1e30f;
        #pragma unroll
        for (int mi = 0; mi < 4; ++mi) {
            #pragma unroll
            for (int p = 0; p < 4; ++p) {
                const int R = wave * 64 + mi * 16 + (lane >> 4) * 4 + p;
                const float d2 = sqr[mi][p] + sc - 2.f * acc[mi][ni][p];
                const float d  = __builtin_amdgcn_sqrtf(fmaxf(d2, 0.f));
                ds += d;
                if ((R >> 3) == Cg) hp = fmaxf(hp, d);
                else                hn = fminf(hn, d);
            }
        }
        // combine the 4 quads (same col, disjoint row subsets)
        #pragma unroll
        for (int off = 16; off < 64; off <<= 1) {
            ds += __shfl_xor(ds, off);
            hp = fmaxf(hp, __shfl_xor(hp, off));
            hn = fminf(hn, __shfl_xor(hn, off));
        }
        if (lane < 16) {
            mrg[wave][ni * 16 + lane][0] = hp;
            mrg[wave][ni * 16 + lane][1] = hn;
            mrg[wave][ni * 16 + lane][2] = ds;
        }
    }
    __syncthreads();
    if (tid < 64) {   // col tid of the slab: merge 8 row-strips + final sum
        float hp = 0.f, hn = 1e30f, bd = 0.f;
        #pragma unroll
        for (int w = 0; w < 8; ++w) {
            hp = fmaxf(hp, mrg[w][tid][0]);
            hn = fminf(hn, mrg[w][tid][1]);
            bd += mrg[w][tid][2];
        }
        float bl = fmaxf(MARGIN + hp - hn, 0.f);
        #pragma unroll
        for (int off = 32; off > 0; off >>= 1) {
            bl += __shfl_xor(bl, off);
            bd += __shfl_xor(bd, off);
        }
        if (lane == 0) {
            atomicAdd(&out[n],           bl * (1.0f / 512.0f));
            atomicAdd(&out[N_PARTS + n], bd * (1.0f / (512.0f * 512.0f)));
        }
    }
}

extern "C" void kernel_launch(void* const* d_in, const int* in_sizes, int n_in,
                              void* d_out, int out_size, void* d_ws, size_t ws_size,
                              hipStream_t stream) {
    const float* feat = (const float*)d_in[0];    // [62, 512, 256] fp32
    float* out = (float*)d_out;                   // [124]

    ushort_t* Fb = (ushort_t*)d_ws;                                   // frag-major bf16
    float* sq    = (float*)((char*)d_ws + (size_t)ROWS * D_DIM * 2);  // row sum-of-squares

    prep_kernel<<<dim3(128 * 64), 256, 0, stream>>>(feat, Fb, sq, out);
    fused_triplet_kernel<<<dim3(512), 512, 0, stream>>>(Fb, sq, out);
}

// Round 12
// 92.413 us; speedup vs baseline: 1.0060x; 1.0060x over previous
//
#include <hip/hip_runtime.h>

#define N_PARTS 62
#define M_SAMP  512
#define D_DIM   256
#define MARGIN  0.2f
#define ROWS    (N_PARTS * M_SAMP)   // 31744
#define PART_ELEMS (M_SAMP * D_DIM)  // 131072 bf16 per part

typedef unsigned short ushort_t;
typedef __attribute__((ext_vector_type(8))) short bf16x8;   // 8 bf16 = 4 VGPRs
typedef __attribute__((ext_vector_type(4))) float f32x4;

__device__ __forceinline__ ushort_t bf16_rne(float f) {
    unsigned u = __float_as_uint(f);
    unsigned r = u + 0x7fffu + ((u >> 16) & 1u);
    return (ushort_t)(r >> 16);
}

// K1 (identical to R11): fp32 -> bf16 (RNE), per-row sum-of-squares of the
// ROUNDED values, zero-init d_out. XCD-affine grid; FRAGMENT-MAJOR output:
// per (part, chunk c=k>>5, row-group g=row>>4) a contiguous 1 KB frag block;
// consuming lane l reads F[g*16+(l&15)][c*32+(l>>4)*8..+7] at base + l*16 B.
__global__ __launch_bounds__(256) void prep_kernel(const float* __restrict__ feat,
                                                   ushort_t* __restrict__ Fb,
                                                   float* __restrict__ sq,
                                                   float* __restrict__ out) {
    const int id = blockIdx.x;       // id = rb*64 + n
    const int n  = id & 63;          // part
    const int rb = id >> 6;          // row-quad within part (0..127)
    if (id == 0 && threadIdx.x < 2 * N_PARTS) out[threadIdx.x] = 0.0f;
    if (n >= N_PARTS) return;
    const int wv   = threadIdx.x >> 6;            // wave -> one row
    const int lane = threadIdx.x & 63;
    const int rp   = rb * 4 + wv;                 // part-local row
    const int row  = n * M_SAMP + rp;             // global row
    const float4 v = ((const float4*)(feat + (size_t)row * D_DIM))[lane];
    ushort4 us;
    us.x = bf16_rne(v.x); us.y = bf16_rne(v.y);
    us.z = bf16_rne(v.z); us.w = bf16_rne(v.w);
    const float fx = __uint_as_float((unsigned)us.x << 16);
    const float fy = __uint_as_float((unsigned)us.y << 16);
    const float fz = __uint_as_float((unsigned)us.z << 16);
    const float fw = __uint_as_float((unsigned)us.w << 16);
    const int c  = lane >> 3;
    const int q  = (lane >> 1) & 3;
    const int g  = rp >> 4;
    const int fl = (rp & 15) | (q << 4);          // frag lane
    *(ushort4*)(Fb + (size_t)n * PART_ELEMS + ((size_t)(c * 32 + g) * 512)
                + fl * 8 + (lane & 1) * 4) = us;
    float ssum = fx * fx + fy * fy + fz * fz + fw * fw;
    #pragma unroll
    for (int off = 32; off > 0; off >>= 1) ssum += __shfl_xor(ssum, off);
    if (lane == 0) sq[row] = ssum;
}

// K2: MAX-MLP K-loop. 256 VGPR budget (__launch_bounds__(512,2)): ALL 64
// A-frag loads issued up front and held live (af[8][4] = 128 VGPRs); B runs a
// 3-buffer pipeline with prefetch distance 2 (48 VGPRs). ~72 loads in flight
// at the loop head -> ONE latency exposure instead of eight. No LDS, no
// barriers in the K-loop. Epilogue = R10/R11 transposed reduction.
__global__ __launch_bounds__(512, 2) void fused_triplet_kernel(const ushort_t* __restrict__ Fb,
                                                               const float* __restrict__ sq,
                                                               float* __restrict__ out) {
    const int id = blockIdx.x;
    const int n  = id & 63;          // part (XCD affinity: id%8 == n%8)
    const int ct = id >> 6;          // col-slab (64 cols)
    if (n >= N_PARTS) return;
    const int tid = threadIdx.x;
    const int wave = tid >> 6, lane = tid & 63;
    const ushort_t* F = Fb + (size_t)n * PART_ELEMS;
    const float* SQ = sq + n * M_SAMP;

    __shared__ float mrg[8][64][3];   // [wave][slab-local col][hp,hn,ds]

    const ushort_t* aptr = F + (size_t)(wave * 4) * 512 + lane * 8;   // A: rows w*64..
    const ushort_t* bptr = F + (size_t)(ct * 4) * 512 + lane * 8;     // B: slab cols

    // All A frags up front: 8 chunks x 4 row-groups, held in registers.
    bf16x8 af[8][4];
    #pragma unroll
    for (int c = 0; c < 8; ++c)
        #pragma unroll
        for (int i = 0; i < 4; ++i)
            af[c][i] = *(const bf16x8*)(aptr + (size_t)c * (32 * 512) + (size_t)i * 512);

    // B pipeline: 3 buffers, prefetch distance 2.
    bf16x8 bf[3][4];
    #pragma unroll
    for (int c = 0; c < 2; ++c)
        #pragma unroll
        for (int i = 0; i < 4; ++i)
            bf[c][i] = *(const bf16x8*)(bptr + (size_t)c * (32 * 512) + (size_t)i * 512);

    f32x4 acc[4][4] = {};
    #pragma unroll
    for (int c = 0; c < 8; ++c) {
        if (c < 6) {   // prefetch chunk c+2
            const int dst = (c + 2) % 3;
            #pragma unroll
            for (int i = 0; i < 4; ++i)
                bf[dst][i] = *(const bf16x8*)(bptr + (size_t)(c + 2) * (32 * 512)
                                              + (size_t)i * 512);
        }
        const int cur = c % 3;
        #pragma unroll
        for (int mi = 0; mi < 4; ++mi)
            #pragma unroll
            for (int ni = 0; ni < 4; ++ni)
                acc[mi][ni] = __builtin_amdgcn_mfma_f32_16x16x32_bf16(
                    af[c][mi], bf[cur][ni], acc[mi][ni], 0, 0, 0);
    }

    // Epilogue (identical to R11). C/D layout: col = lane&15, row = (lane>>4)*4+reg.
    float sqr[4][4];
    #pragma unroll
    for (int mi = 0; mi < 4; ++mi)
        #pragma unroll
        for (int p = 0; p < 4; ++p)
            sqr[mi][p] = SQ[wave * 64 + mi * 16 + (lane >> 4) * 4 + p];

    #pragma unroll
    for (int ni = 0; ni < 4; ++ni) {
        const int C = ct * 64 + ni * 16 + (lane & 15);   // part-local col
        const float sc = SQ[C];
        const int Cg = C >> 3;                            // label = m>>3
        float ds = 0.f, hp = 0.f, hn = 1e30f;
        #pragma unroll
        for (int mi = 0; mi < 4; ++mi) {
            #pragma unroll
            for (int p = 0; p < 4; ++p) {
                const int R = wave * 64 + mi * 16 + (lane >> 4) * 4 + p;
                const float d2 = sqr[mi][p] + sc - 2.f * acc[mi][ni][p];
                const float d  = __builtin_amdgcn_sqrtf(fmaxf(d2, 0.f));
                ds += d;
                if ((R >> 3) == Cg) hp = fmaxf(hp, d);
                else                hn = fminf(hn, d);
            }
        }
        #pragma unroll
        for (int off = 16; off < 64; off <<= 1) {
            ds += __shfl_xor(ds, off);
            hp = fmaxf(hp, __shfl_xor(hp, off));
            hn = fminf(hn, __shfl_xor(hn, off));
        }
        if (lane < 16) {
            mrg[wave][ni * 16 + lane][0] = hp;
            mrg[wave][ni * 16 + lane][1] = hn;
            mrg[wave][ni * 16 + lane][2] = ds;
        }
    }
    __syncthreads();
    if (tid < 64) {   // col tid of the slab: merge 8 row-strips + final sum
        float hp = 0.f, hn = 1e30f, bd = 0.f;
        #pragma unroll
        for (int w = 0; w < 8; ++w) {
            hp = fmaxf(hp, mrg[w][tid][0]);
            hn = fminf(hn, mrg[w][tid][1]);
            bd += mrg[w][tid][2];
        }
        float bl = fmaxf(MARGIN + hp - hn, 0.f);
        #pragma unroll
        for (int off = 32; off > 0; off >>= 1) {
            bl += __shfl_xor(bl, off);
            bd += __shfl_xor(bd, off);
        }
        if (lane == 0) {
            atomicAdd(&out[n],           bl * (1.0f / 512.0f));
            atomicAdd(&out[N_PARTS + n], bd * (1.0f / (512.0f * 512.0f)));
        }
    }
}

extern "C" void kernel_launch(void* const* d_in, const int* in_sizes, int n_in,
                              void* d_out, int out_size, void* d_ws, size_t ws_size,
                              hipStream_t stream) {
    const float* feat = (const float*)d_in[0];    // [62, 512, 256] fp32
    float* out = (float*)d_out;                   // [124]

    ushort_t* Fb = (ushort_t*)d_ws;                                   // frag-major bf16
    float* sq    = (float*)((char*)d_ws + (size_t)ROWS * D_DIM * 2);  // row sum-of-squares

    prep_kernel<<<dim3(128 * 64), 256, 0, stream>>>(feat, Fb, sq, out);
    fused_triplet_kernel<<<dim3(512), 512, 0, stream>>>(Fb, sq, out);
}

// Round 13
// 91.148 us; speedup vs baseline: 1.0199x; 1.0139x over previous
//
#include <hip/hip_runtime.h>

#define N_PARTS 62
#define M_SAMP  512
#define D_DIM   256
#define MARGIN  0.2f
#define ROWS    (N_PARTS * M_SAMP)   // 31744
#define PART_ELEMS (M_SAMP * D_DIM)  // 131072 bf16 per part

typedef unsigned short ushort_t;
typedef __attribute__((ext_vector_type(8))) short bf16x8;   // 8 bf16 = 4 VGPRs
typedef __attribute__((ext_vector_type(4))) float f32x4;

__device__ __forceinline__ ushort_t bf16_rne(float f) {
    unsigned u = __float_as_uint(f);
    unsigned r = u + 0x7fffu + ((u >> 16) & 1u);
    return (ushort_t)(r >> 16);
}

// K1 (identical to R11/R12): fp32 -> bf16 (RNE), per-row sum-of-squares of
// the ROUNDED values, zero-init d_out. FRAGMENT-MAJOR output: per (part,
// chunk c=k>>5, row-group g=row>>4) a contiguous 1 KB frag block; consuming
// lane l reads F[g*16+(l&15)][c*32+(l>>4)*8..+7] at base + l*16 B.
__global__ __launch_bounds__(256) void prep_kernel(const float* __restrict__ feat,
                                                   ushort_t* __restrict__ Fb,
                                                   float* __restrict__ sq,
                                                   float* __restrict__ out) {
    const int id = blockIdx.x;       // id = rb*64 + n
    const int n  = id & 63;          // part
    const int rb = id >> 6;          // row-quad within part (0..127)
    if (id == 0 && threadIdx.x < 2 * N_PARTS) out[threadIdx.x] = 0.0f;
    if (n >= N_PARTS) return;
    const int wv   = threadIdx.x >> 6;            // wave -> one row
    const int lane = threadIdx.x & 63;
    const int rp   = rb * 4 + wv;                 // part-local row
    const int row  = n * M_SAMP + rp;             // global row
    const float4 v = ((const float4*)(feat + (size_t)row * D_DIM))[lane];
    ushort4 us;
    us.x = bf16_rne(v.x); us.y = bf16_rne(v.y);
    us.z = bf16_rne(v.z); us.w = bf16_rne(v.w);
    const float fx = __uint_as_float((unsigned)us.x << 16);
    const float fy = __uint_as_float((unsigned)us.y << 16);
    const float fz = __uint_as_float((unsigned)us.z << 16);
    const float fw = __uint_as_float((unsigned)us.w << 16);
    const int c  = lane >> 3;
    const int q  = (lane >> 1) & 3;
    const int g  = rp >> 4;
    const int fl = (rp & 15) | (q << 4);          // frag lane
    *(ushort4*)(Fb + (size_t)n * PART_ELEMS + ((size_t)(c * 32 + g) * 512)
                + fl * 8 + (lane & 1) * 4) = us;
    float ssum = fx * fx + fy * fy + fz * fz + fw * fw;
    #pragma unroll
    for (int off = 32; off > 0; off >>= 1) ssum += __shfl_xor(ssum, off);
    if (lane == 0) sq[row] = ssum;
}

// K2: WIDE blocks — 128 cols per block (grid 62x4 = 248, XCD-affine id%8).
// Wave w owns rows w*64..+63 x the block's 128 cols: acc[4][8]. A-panel is
// re-read 4x per part instead of 8x: L2/L3 traffic 143 -> 79 MB.
// Transposed register reduction (dist symmetry) as in R10-R12.
__global__ __launch_bounds__(512, 2) void fused_triplet_kernel(const ushort_t* __restrict__ Fb,
                                                               const float* __restrict__ sq,
                                                               float* __restrict__ out) {
    const int id = blockIdx.x;
    const int n  = id & 63;          // part (XCD affinity: id%8 == n%8)
    const int ct = id >> 6;          // col-slab (128 cols)
    if (n >= N_PARTS) return;
    const int tid = threadIdx.x;
    const int wave = tid >> 6, lane = tid & 63;
    const ushort_t* F = Fb + (size_t)n * PART_ELEMS;
    const float* SQ = sq + n * M_SAMP;

    __shared__ float mrg[8][128][3];   // [wave][slab-local col][hp,hn,ds]

    const ushort_t* aptr = F + (size_t)(wave * 4) * 512 + lane * 8;   // A: rows w*64..
    const ushort_t* bptr = F + (size_t)(ct * 8) * 512 + lane * 8;     // B: 128 slab cols

    f32x4 acc[4][8] = {};

    #pragma unroll
    for (int c = 0; c < 8; ++c) {
        const size_t off = (size_t)c * (32 * 512);
        bf16x8 af[4], bf[8];
        #pragma unroll
        for (int i = 0; i < 4; ++i)
            af[i] = *(const bf16x8*)(aptr + off + (size_t)i * 512);
        #pragma unroll
        for (int i = 0; i < 8; ++i)
            bf[i] = *(const bf16x8*)(bptr + off + (size_t)i * 512);
        #pragma unroll
        for (int mi = 0; mi < 4; ++mi)
            #pragma unroll
            for (int ni = 0; ni < 8; ++ni)
                acc[mi][ni] = __builtin_amdgcn_mfma_f32_16x16x32_bf16(
                    af[mi], bf[ni], acc[mi][ni], 0, 0, 0);
    }

    // Epilogue: transposed reduction. C/D layout: col = lane&15,
    // row = (lane>>4)*4 + reg (verified R2-R12).
    float sqr[4][4];
    #pragma unroll
    for (int mi = 0; mi < 4; ++mi)
        #pragma unroll
        for (int p = 0; p < 4; ++p)
            sqr[mi][p] = SQ[wave * 64 + mi * 16 + (lane >> 4) * 4 + p];

    #pragma unroll
    for (int ni = 0; ni < 8; ++ni) {
        const int C = ct * 128 + ni * 16 + (lane & 15);   // part-local col
        const float sc = SQ[C];
        const int Cg = C >> 3;                             // label = m>>3
        float ds = 0.f, hp = 0.f, hn = 1e30f;
        #pragma unroll
        for (int mi = 0; mi < 4; ++mi) {
            #pragma unroll
            for (int p = 0; p < 4; ++p) {
                const int R = wave * 64 + mi * 16 + (lane >> 4) * 4 + p;
                const float d2 = sqr[mi][p] + sc - 2.f * acc[mi][ni][p];
                const float d  = __builtin_amdgcn_sqrtf(fmaxf(d2, 0.f));
                ds += d;
                if ((R >> 3) == Cg) hp = fmaxf(hp, d);
                else                hn = fminf(hn, d);
            }
        }
        // combine the 4 quads (same col, disjoint row subsets)
        #pragma unroll
        for (int off = 16; off < 64; off <<= 1) {
            ds += __shfl_xor(ds, off);
            hp = fmaxf(hp, __shfl_xor(hp, off));
            hn = fminf(hn, __shfl_xor(hn, off));
        }
        if (lane < 16) {
            mrg[wave][ni * 16 + lane][0] = hp;
            mrg[wave][ni * 16 + lane][1] = hn;
            mrg[wave][ni * 16 + lane][2] = ds;
        }
    }
    __syncthreads();
    if (tid < 128) {   // col tid of the slab: merge 8 row-strips
        float hp = 0.f, hn = 1e30f, bd = 0.f;
        #pragma unroll
        for (int w = 0; w < 8; ++w) {
            hp = fmaxf(hp, mrg[w][tid][0]);
            hn = fminf(hn, mrg[w][tid][1]);
            bd += mrg[w][tid][2];
        }
        const float bl = fmaxf(MARGIN + hp - hn, 0.f);
        // reuse mrg row 0 for the final block reduction
        mrg[0][tid][0] = bl;
        mrg[0][tid][1] = bd;
    }
    __syncthreads();
    if (tid < 64) {
        float bl = mrg[0][tid][0] + mrg[0][tid + 64][0];
        float bd = mrg[0][tid][1] + mrg[0][tid + 64][1];
        #pragma unroll
        for (int off = 32; off > 0; off >>= 1) {
            bl += __shfl_xor(bl, off);
            bd += __shfl_xor(bd, off);
        }
        if (lane == 0) {
            atomicAdd(&out[n],           bl * (1.0f / 512.0f));
            atomicAdd(&out[N_PARTS + n], bd * (1.0f / (512.0f * 512.0f)));
        }
    }
}

extern "C" void kernel_launch(void* const* d_in, const int* in_sizes, int n_in,
                              void* d_out, int out_size, void* d_ws, size_t ws_size,
                              hipStream_t stream) {
    const float* feat = (const float*)d_in[0];    // [62, 512, 256] fp32
    float* out = (float*)d_out;                   // [124]

    ushort_t* Fb = (ushort_t*)d_ws;                                   // frag-major bf16
    float* sq    = (float*)((char*)d_ws + (size_t)ROWS * D_DIM * 2);  // row sum-of-squares

    prep_kernel<<<dim3(128 * 64), 256, 0, stream>>>(feat, Fb, sq, out);
    fused_triplet_kernel<<<dim3(4 * 64), 512, 0, stream>>>(Fb, sq, out);
}